// Round 13
// baseline (167.313 us; speedup 1.0000x reference)
//
#include <hip/hip_runtime.h>
#include <stdint.h>

#define D_DIM 1024
#define INV_T 14.2857142857142857f
#define QSCALE 32.0f
#define EPI_SCALE (INV_T / (QSCALE * QSCALE))   // dequant (32a)(32b) + /T
#define BK 64
#define NT (D_DIM / BK)   // 16 K-tiles

typedef __attribute__((ext_vector_type(4))) float f32x4;
typedef __attribute__((ext_vector_type(2))) long lx2;

// ---------------- Kernel 1: L2-normalize rows (fp32 -> fp8 e4m3 x32) + diagonal dot + S zeroing ----------------
// Output layout: per row, per 64B k-block kb: 4 chunks of 16B; chunk c =
//   bytes k[kb*64 + c*8 .. +8]  ||  k[kb*64 + 32 + c*8 .. +8]
// (k-interleave so one ds_read_b128 yields both K=32 MFMA steps; uniform
//  k-relabel applied to BOTH operands -> GEMM result unchanged.)
__global__ __launch_bounds__(256) void norm_diag_kernel(
    const float* __restrict__ A, const float* __restrict__ T,
    unsigned int* __restrict__ An, unsigned int* __restrict__ Tn,
    float* __restrict__ diag, float* __restrict__ Srow, float* __restrict__ Scol)
{
  const int row = blockIdx.x;
  const int tid = threadIdx.x;              // 256 threads x 4 elems (D=1024)
  const size_t base = (size_t)row * D_DIM;
  const float4 av = ((const float4*)(A + base))[tid];
  const float4 tv = ((const float4*)(T + base))[tid];
  float sa = av.x*av.x + av.y*av.y + av.z*av.z + av.w*av.w;
  float st = tv.x*tv.x + tv.y*tv.y + tv.z*tv.z + tv.w*tv.w;
  float sd = av.x*tv.x + av.y*tv.y + av.z*tv.z + av.w*tv.w;
  #pragma unroll
  for (int m = 1; m < 64; m <<= 1) {
    sa += __shfl_xor(sa, m, 64);
    st += __shfl_xor(st, m, 64);
    sd += __shfl_xor(sd, m, 64);
  }
  __shared__ float red[3][4];
  const int wid = tid >> 6;
  if ((tid & 63) == 0) { red[0][wid] = sa; red[1][wid] = st; red[2][wid] = sd; }
  __syncthreads();
  sa = red[0][0] + red[0][1] + red[0][2] + red[0][3];
  st = red[1][0] + red[1][1] + red[1][2] + red[1][3];
  sd = red[2][0] + red[2][1] + red[2][2] + red[2][3];
  const float ra = rsqrtf(sa), rt = rsqrtf(st);
  if (tid == 0) {
    diag[row] = sd * ra * rt * INV_T;   // diag term in exact fp32
    Srow[row] = 0.f;                    // zero accumulators (norm precedes gemm)
    Scol[row] = 0.f;
  }
  const float qa = ra * QSCALE, qt = rt * QSCALE;
  unsigned int ao = __builtin_amdgcn_cvt_pk_fp8_f32(av.x*qa, av.y*qa, 0, 0);
  ao = __builtin_amdgcn_cvt_pk_fp8_f32(av.z*qa, av.w*qa, ao, 1);
  unsigned int to = __builtin_amdgcn_cvt_pk_fp8_f32(tv.x*qt, tv.y*qt, 0, 0);
  to = __builtin_amdgcn_cvt_pk_fp8_f32(tv.z*qt, tv.w*qt, to, 1);
  // thread's 4 bytes = k [4*tid .. 4*tid+3]; interleaved u32 index:
  const int idx = (tid & ~15) + ((tid >> 1) & 3) * 4 + ((tid >> 3) & 1) * 2 + (tid & 1);
  An[row * 256 + idx] = ao;
  Tn[row * 256 + idx] = to;
}

// ---------------- Kernel 2: 128x128 fp8 double-buffered fused GEMM + exp + row/col sum-exp ----------------
__device__ __forceinline__ void gload_lds16(const void* g, void* l) {
  __builtin_amdgcn_global_load_lds(
      (const __attribute__((address_space(1))) unsigned int*)g,
      (__attribute__((address_space(3))) unsigned int*)l, 16, 0, 0);
}

#define SBAR asm volatile("s_barrier" ::: "memory")

// Stage tile T (both operands) into buf (T&1). Per operand: 128 rows x 64 B
// = 512 16B-chunks, 2 per thread (4 vmcnt ops/thread total).
// LDS dest linear; swizzle on the GLOBAL source: LDS chunk (r,c) holds
// global chunk (r, c ^ ((r>>1)&3)) [rule #21, both sides].
#define STAGE2(T) do {                                                          \
    const unsigned char* _a = aP + (size_t)(T) * BK;                            \
    const unsigned char* _b = bP + (size_t)(T) * BK;                            \
    const int _bb = ((T) & 1) * 16384;                                          \
    _Pragma("unroll")                                                           \
    for (int _i = 0; _i < 2; ++_i) {                                            \
      const int _ci = _i*256 + tid;                                             \
      const int _r = _ci >> 2, _c = _ci & 3;                                    \
      const size_t _go = (size_t)_r * D_DIM + ((_c ^ ((_r >> 1) & 3)) << 4);    \
      gload_lds16(_a + _go, &lds[_bb + _ci*16]);                                \
      gload_lds16(_b + _go, &lds[_bb + 8192 + _ci*16]);                         \
    }                                                                           \
  } while (0)

__global__ __launch_bounds__(256, 4) void gemm_lse_kernel(
    const unsigned char* __restrict__ An, const unsigned char* __restrict__ Tn,
    float* __restrict__ Srow, float* __restrict__ Scol, int nbc)
{
  // [buf(2)][op(2)][128 rows][64 B] = 32 KB
  __shared__ unsigned char lds[32768];

  // XCD-aware bijective swizzle (gridDim.x = 4096, %8 == 0)
  const int nwg = gridDim.x;
  const int bid = blockIdx.x;
  const int cpx = nwg >> 3;
  const int swz = (bid & 7) * cpx + (bid >> 3);
  const int brow = swz / nbc;
  const int bcol = swz - brow * nbc;

  const int tid  = threadIdx.x;
  const int lane = tid & 63;
  const int wid  = tid >> 6;        // 4 waves, 2x2; each wave owns 64x64 output
  const int wr   = wid >> 1, wc = wid & 1;
  const int lcol = lane & 15, lrow = lane >> 4;

  const unsigned char* aP = An + (size_t)brow * 128 * D_DIM;
  const unsigned char* bP = Tn + (size_t)bcol * 128 * D_DIM;

  f32x4 acc[4][4] = {};

  // Prologue: tile0 -> buf0; drain; barrier.
  STAGE2(0);
  asm volatile("s_waitcnt vmcnt(0)" ::: "memory");
  SBAR;

  // Minimal 2-phase (catalog T3 recipe): per tile, FIRST issue next-tile
  // staging into the other buffer (overlaps with this tile's ds_reads+MFMA),
  // then read+MFMA this tile, then ONE vmcnt(0)+barrier.
  // Safety: buf[(t+1)&1]'s readers (tile t-1) were sealed by iter t-1's
  // barrier; this iter's ds_reads complete before MFMA issue (lgkmcnt);
  // vmcnt(0) drains loads issued ~one MFMA-phase earlier (latency covered).
  for (int t = 0; t < NT; ++t) {
    const int bb = (t & 1) * 16384;
    if (t + 1 < NT) STAGE2(t + 1);
    // One b128 per fragment: chunk c = lrow ^ ((row>>1)&3); lo 8B = kk0 octet
    // (k = lrow*8..), hi 8B = kk1 octet (k = 32+lrow*8..) via the k-interleave.
    lx2 a2[4], b2[4];
    #pragma unroll
    for (int m = 0; m < 4; ++m) {
      const int row = wr*64 + m*16 + lcol;
      const int c = lrow ^ ((row >> 1) & 3);
      a2[m] = *(const lx2*)&lds[bb + row*64 + c*16];
    }
    #pragma unroll
    for (int n = 0; n < 4; ++n) {
      const int row = wc*64 + n*16 + lcol;
      const int c = lrow ^ ((row >> 1) & 3);
      b2[n] = *(const lx2*)&lds[bb + 8192 + row*64 + c*16];
    }
    #pragma unroll
    for (int m = 0; m < 4; ++m)
      #pragma unroll
      for (int n = 0; n < 4; ++n)
        acc[m][n] = __builtin_amdgcn_mfma_f32_16x16x32_fp8_fp8(a2[m][0], b2[n][0], acc[m][n], 0, 0, 0);
    #pragma unroll
    for (int m = 0; m < 4; ++m)
      #pragma unroll
      for (int n = 0; n < 4; ++n)
        acc[m][n] = __builtin_amdgcn_mfma_f32_16x16x32_fp8_fp8(a2[m][1], b2[n][1], acc[m][n], 0, 0, 0);
    asm volatile("s_waitcnt vmcnt(0)" ::: "memory");  // next tile resident
    SBAR;                                             // seals this buf's reads
  }

  // ---- Epilogue: e = exp(acc * EPI_SCALE); row/col partial sums -> atomics ----
  // C/D mapping (dtype-independent): col = lane&15, row = (lane>>4)*4 + reg
  float rowsum[4][4];
  float colsum[4];
  #pragma unroll
  for (int m = 0; m < 4; ++m)
    #pragma unroll
    for (int r = 0; r < 4; ++r) rowsum[m][r] = 0.f;
  #pragma unroll
  for (int n = 0; n < 4; ++n) {
    float cs = 0.f;
    #pragma unroll
    for (int m = 0; m < 4; ++m)
      #pragma unroll
      for (int r = 0; r < 4; ++r) {
        const float e = __expf(acc[m][n][r] * EPI_SCALE);
        rowsum[m][r] += e;
        cs += e;
      }
    colsum[n] = cs;
  }
  #pragma unroll
  for (int m = 0; m < 4; ++m)
    #pragma unroll
    for (int r = 0; r < 4; ++r) {
      float v = rowsum[m][r];
      v += __shfl_xor(v, 1, 64);
      v += __shfl_xor(v, 2, 64);
      v += __shfl_xor(v, 4, 64);
      v += __shfl_xor(v, 8, 64);
      if (lcol == 0)
        atomicAdd(&Srow[brow*128 + wr*64 + m*16 + lrow*4 + r], v);
    }
  #pragma unroll
  for (int n = 0; n < 4; ++n) {
    float v = colsum[n];
    v += __shfl_xor(v, 16, 64);
    v += __shfl_xor(v, 32, 64);
    if (lane < 16)
      atomicAdd(&Scol[bcol*128 + wc*64 + n*16 + lcol], v);
  }
}

// ---------------- Kernel 3: loss = mean(0.5*(log Srow + log Scol) - diag) ----------------
__global__ __launch_bounds__(256) void loss_kernel(
    const float* __restrict__ Srow, const float* __restrict__ Scol,
    const float* __restrict__ diag, float* __restrict__ out, int B)
{
  float s = 0.f;
  for (int i = threadIdx.x; i < B; i += 256)
    s += 0.5f * (__logf(Srow[i]) + __logf(Scol[i])) - diag[i];
  #pragma unroll
  for (int m = 1; m < 64; m <<= 1) s += __shfl_xor(s, m, 64);
  __shared__ float red[4];
  if ((threadIdx.x & 63) == 0) red[threadIdx.x >> 6] = s;
  __syncthreads();
  if (threadIdx.x == 0) out[0] = (red[0] + red[1] + red[2] + red[3]) / (float)B;
}

extern "C" void kernel_launch(void* const* d_in, const int* in_sizes, int n_in,
                              void* d_out, int out_size, void* d_ws, size_t ws_size,
                              hipStream_t stream) {
  const float* A = (const float*)d_in[0];
  const float* T = (const float*)d_in[1];
  const int B = in_sizes[0] / D_DIM;     // 8192
  const int nbc = B / 128;               // 64

  char* ws = (char*)d_ws;
  unsigned char* An = (unsigned char*)ws;                       // B*D fp8 = 8 MB
  unsigned char* Tn = An + (size_t)B * D_DIM;                   // 8 MB
  float* Srow = (float*)(ws + (size_t)2 * B * D_DIM);
  float* Scol = Srow + B;
  float* diag = Scol + B;

  norm_diag_kernel<<<B, 256, 0, stream>>>(A, T, (unsigned int*)An, (unsigned int*)Tn,
                                          diag, Srow, Scol);
  gemm_lse_kernel<<<nbc * nbc, 256, 0, stream>>>(An, Tn, Srow, Scol, nbc);
  loss_kernel<<<1, 256, 0, stream>>>(Srow, Scol, diag, (float*)d_out, B);
}

// Round 14
// 156.987 us; speedup vs baseline: 1.0658x; 1.0658x over previous
//
#include <hip/hip_runtime.h>
#include <stdint.h>

#define D_DIM 1024
#define INV_T 14.2857142857142857f
#define QSCALE 32.0f
#define EPI_SCALE (INV_T / (QSCALE * QSCALE))   // dequant (32a)(32b) + /T
#define BK 64
#define NT (D_DIM / BK)   // 16 K-tiles

typedef __attribute__((ext_vector_type(4))) float f32x4;
typedef __attribute__((ext_vector_type(2))) long lx2;

// ---------------- Kernel 1: L2-normalize rows (fp32 -> fp8 e4m3 x32) + diagonal dot + S zeroing ----------------
// Output layout: per row, per 64B k-block kb: 4 chunks of 16B; chunk c =
//   bytes k[kb*64 + c*8 .. +8]  ||  k[kb*64 + 32 + c*8 .. +8]
// (k-interleave so one ds_read_b128 yields both K=32 MFMA steps; uniform
//  k-relabel applied to BOTH operands -> GEMM result unchanged.)
__global__ __launch_bounds__(256) void norm_diag_kernel(
    const float* __restrict__ A, const float* __restrict__ T,
    unsigned int* __restrict__ An, unsigned int* __restrict__ Tn,
    float* __restrict__ diag, float* __restrict__ Srow, float* __restrict__ Scol)
{
  const int row = blockIdx.x;
  const int tid = threadIdx.x;              // 256 threads x 4 elems (D=1024)
  const size_t base = (size_t)row * D_DIM;
  const float4 av = ((const float4*)(A + base))[tid];
  const float4 tv = ((const float4*)(T + base))[tid];
  float sa = av.x*av.x + av.y*av.y + av.z*av.z + av.w*av.w;
  float st = tv.x*tv.x + tv.y*tv.y + tv.z*tv.z + tv.w*tv.w;
  float sd = av.x*tv.x + av.y*tv.y + av.z*tv.z + av.w*tv.w;
  #pragma unroll
  for (int m = 1; m < 64; m <<= 1) {
    sa += __shfl_xor(sa, m, 64);
    st += __shfl_xor(st, m, 64);
    sd += __shfl_xor(sd, m, 64);
  }
  __shared__ float red[3][4];
  const int wid = tid >> 6;
  if ((tid & 63) == 0) { red[0][wid] = sa; red[1][wid] = st; red[2][wid] = sd; }
  __syncthreads();
  sa = red[0][0] + red[0][1] + red[0][2] + red[0][3];
  st = red[1][0] + red[1][1] + red[1][2] + red[1][3];
  sd = red[2][0] + red[2][1] + red[2][2] + red[2][3];
  const float ra = rsqrtf(sa), rt = rsqrtf(st);
  if (tid == 0) {
    diag[row] = sd * ra * rt * INV_T;   // diag term in exact fp32
    Srow[row] = 0.f;                    // zero accumulators (norm precedes gemm)
    Scol[row] = 0.f;
  }
  const float qa = ra * QSCALE, qt = rt * QSCALE;
  unsigned int ao = __builtin_amdgcn_cvt_pk_fp8_f32(av.x*qa, av.y*qa, 0, 0);
  ao = __builtin_amdgcn_cvt_pk_fp8_f32(av.z*qa, av.w*qa, ao, 1);
  unsigned int to = __builtin_amdgcn_cvt_pk_fp8_f32(tv.x*qt, tv.y*qt, 0, 0);
  to = __builtin_amdgcn_cvt_pk_fp8_f32(tv.z*qt, tv.w*qt, to, 1);
  // thread's 4 bytes = k [4*tid .. 4*tid+3]; interleaved u32 index:
  const int idx = (tid & ~15) + ((tid >> 1) & 3) * 4 + ((tid >> 3) & 1) * 2 + (tid & 1);
  An[row * 256 + idx] = ao;
  Tn[row * 256 + idx] = to;
}

// ---------------- Kernel 2: 128x128 fp8 double-buffered fused GEMM + exp + row/col sum-exp ----------------
__device__ __forceinline__ void gload_lds16(const void* g, void* l) {
  __builtin_amdgcn_global_load_lds(
      (const __attribute__((address_space(1))) unsigned int*)g,
      (__attribute__((address_space(3))) unsigned int*)l, 16, 0, 0);
}

#define SBAR asm volatile("s_barrier" ::: "memory")

// Stage tile T (both operands) into buf (T&1). Per operand: 128 rows x 64 B
// = 512 16B-chunks, 2 per thread (4 vmcnt ops/thread total).
// LDS dest linear; swizzle on the GLOBAL source: LDS chunk (r,c) holds
// global chunk (r, c ^ ((r>>1)&3)) [rule #21, both sides].
#define STAGE2(T) do {                                                          \
    const unsigned char* _a = aP + (size_t)(T) * BK;                            \
    const unsigned char* _b = bP + (size_t)(T) * BK;                            \
    const int _bb = ((T) & 1) * 16384;                                          \
    _Pragma("unroll")                                                           \
    for (int _i = 0; _i < 2; ++_i) {                                            \
      const int _ci = _i*256 + tid;                                             \
      const int _r = _ci >> 2, _c = _ci & 3;                                    \
      const size_t _go = (size_t)_r * D_DIM + ((_c ^ ((_r >> 1) & 3)) << 4);    \
      gload_lds16(_a + _go, &lds[_bb + _ci*16]);                                \
      gload_lds16(_b + _go, &lds[_bb + 8192 + _ci*16]);                         \
    }                                                                           \
  } while (0)

__global__ __launch_bounds__(256, 4) void gemm_lse_kernel(
    const unsigned char* __restrict__ An, const unsigned char* __restrict__ Tn,
    float* __restrict__ Srow, float* __restrict__ Scol, int nbc)
{
  // [buf(2)][op(2)][128 rows][64 B] = 32 KB
  __shared__ unsigned char lds[32768];

  // XCD-aware bijective swizzle (gridDim.x = 4096, %8 == 0)
  const int nwg = gridDim.x;
  const int bid = blockIdx.x;
  const int cpx = nwg >> 3;
  const int swz = (bid & 7) * cpx + (bid >> 3);
  const int brow = swz / nbc;
  const int bcol = swz - brow * nbc;

  const int tid  = threadIdx.x;
  const int lane = tid & 63;
  const int wid  = tid >> 6;        // 4 waves, 2x2; each wave owns 64x64 output
  const int wr   = wid >> 1, wc = wid & 1;
  const int lcol = lane & 15, lrow = lane >> 4;

  const unsigned char* aP = An + (size_t)brow * 128 * D_DIM;
  const unsigned char* bP = Tn + (size_t)bcol * 128 * D_DIM;

  f32x4 acc[4][4] = {};

  // Prologue: tile0 -> buf0, tile1 -> buf1; vmcnt(4) waits tile0's 4
  // (in-order retirement), keeps tile1's 4 in flight.
  STAGE2(0);
  STAGE2(1);
  asm volatile("s_waitcnt vmcnt(4)" ::: "memory");
  SBAR;

  for (int t = 0; t < NT; ++t) {
    const int bb = (t & 1) * 16384;
    // One b128 per fragment: chunk c = lrow ^ ((row>>1)&3); lo 8B = kk0 octet
    // (k = lrow*8..), hi 8B = kk1 octet (k = 32+lrow*8..) via the k-interleave.
    lx2 a2[4], b2[4];
    #pragma unroll
    for (int m = 0; m < 4; ++m) {
      const int row = wr*64 + m*16 + lcol;
      const int c = lrow ^ ((row >> 1) & 3);
      a2[m] = *(const lx2*)&lds[bb + row*64 + c*16];
    }
    #pragma unroll
    for (int n = 0; n < 4; ++n) {
      const int row = wc*64 + n*16 + lcol;
      const int c = lrow ^ ((row >> 1) & 3);
      b2[n] = *(const lx2*)&lds[bb + 8192 + row*64 + c*16];
    }
    #pragma unroll
    for (int m = 0; m < 4; ++m)
      #pragma unroll
      for (int n = 0; n < 4; ++n)
        acc[m][n] = __builtin_amdgcn_mfma_f32_16x16x32_fp8_fp8(a2[m][0], b2[n][0], acc[m][n], 0, 0, 0);
    #pragma unroll
    for (int m = 0; m < 4; ++m)
      #pragma unroll
      for (int n = 0; n < 4; ++n)
        acc[m][n] = __builtin_amdgcn_mfma_f32_16x16x32_fp8_fp8(a2[m][1], b2[n][1], acc[m][n], 0, 0, 0);
    // Seal all waves' reads of this buf, then refill it with tile t+2.
    SBAR;
    if (t + 2 < NT) {
      STAGE2(t + 2);
      // Outstanding: t+1's 4 + t+2's 4. Wait t+1 resident (loads issued two
      // compute phases ago -> latency fully covered); keep t+2 in flight.
      asm volatile("s_waitcnt vmcnt(4)" ::: "memory");
    } else {
      asm volatile("s_waitcnt vmcnt(0)" ::: "memory");
    }
    SBAR;
  }

  // ---- Epilogue: e = exp(acc * EPI_SCALE); row/col partial sums -> atomics ----
  // C/D mapping (dtype-independent): col = lane&15, row = (lane>>4)*4 + reg
  float rowsum[4][4];
  float colsum[4];
  #pragma unroll
  for (int m = 0; m < 4; ++m)
    #pragma unroll
    for (int r = 0; r < 4; ++r) rowsum[m][r] = 0.f;
  #pragma unroll
  for (int n = 0; n < 4; ++n) {
    float cs = 0.f;
    #pragma unroll
    for (int m = 0; m < 4; ++m)
      #pragma unroll
      for (int r = 0; r < 4; ++r) {
        const float e = __expf(acc[m][n][r] * EPI_SCALE);
        rowsum[m][r] += e;
        cs += e;
      }
    colsum[n] = cs;
  }
  #pragma unroll
  for (int m = 0; m < 4; ++m)
    #pragma unroll
    for (int r = 0; r < 4; ++r) {
      float v = rowsum[m][r];
      v += __shfl_xor(v, 1, 64);
      v += __shfl_xor(v, 2, 64);
      v += __shfl_xor(v, 4, 64);
      v += __shfl_xor(v, 8, 64);
      if (lcol == 0)
        atomicAdd(&Srow[brow*128 + wr*64 + m*16 + lrow*4 + r], v);
    }
  #pragma unroll
  for (int n = 0; n < 4; ++n) {
    float v = colsum[n];
    v += __shfl_xor(v, 16, 64);
    v += __shfl_xor(v, 32, 64);
    if (lane < 16)
      atomicAdd(&Scol[bcol*128 + wc*64 + n*16 + lcol], v);
  }
}

// ---------------- Kernel 3: loss = mean(0.5*(log Srow + log Scol) - diag) ----------------
__global__ __launch_bounds__(256) void loss_kernel(
    const float* __restrict__ Srow, const float* __restrict__ Scol,
    const float* __restrict__ diag, float* __restrict__ out, int B)
{
  float s = 0.f;
  for (int i = threadIdx.x; i < B; i += 256)
    s += 0.5f * (__logf(Srow[i]) + __logf(Scol[i])) - diag[i];
  #pragma unroll
  for (int m = 1; m < 64; m <<= 1) s += __shfl_xor(s, m, 64);
  __shared__ float red[4];
  if ((threadIdx.x & 63) == 0) red[threadIdx.x >> 6] = s;
  __syncthreads();
  if (threadIdx.x == 0) out[0] = (red[0] + red[1] + red[2] + red[3]) / (float)B;
}

extern "C" void kernel_launch(void* const* d_in, const int* in_sizes, int n_in,
                              void* d_out, int out_size, void* d_ws, size_t ws_size,
                              hipStream_t stream) {
  const float* A = (const float*)d_in[0];
  const float* T = (const float*)d_in[1];
  const int B = in_sizes[0] / D_DIM;     // 8192
  const int nbc = B / 128;               // 64

  char* ws = (char*)d_ws;
  unsigned char* An = (unsigned char*)ws;                       // B*D fp8 = 8 MB
  unsigned char* Tn = An + (size_t)B * D_DIM;                   // 8 MB
  float* Srow = (float*)(ws + (size_t)2 * B * D_DIM);
  float* Scol = Srow + B;
  float* diag = Scol + B;

  norm_diag_kernel<<<B, 256, 0, stream>>>(A, T, (unsigned int*)An, (unsigned int*)Tn,
                                          diag, Srow, Scol);
  gemm_lse_kernel<<<nbc * nbc, 256, 0, stream>>>(An, Tn, Srow, Scol, nbc);
  loss_kernel<<<1, 256, 0, stream>>>(Srow, Scol, diag, (float*)d_out, B);
}